// Round 8
// baseline (143.099 us; speedup 1.0000x reference)
//
#include <hip/hip_runtime.h>
#include <math.h>

// Problem constants: B=32, S=2048, C=16, E=8, H=16
#define NB 32
#define NS 2048
#define NC 16
#define NE 8
#define NH 16
#define KSL 32            // K-slices for gate partial GEMM (64 s per slice)

// ---------------------------------------------------------------------------
// Kernel A1: gate partial sums.  g_pre[r=(b,c)][e16] = sum_K x2[r][K]*W[e16][K]
// x2[(b,c)][2s+t] = x[b,s,c,t]; e16<8 -> Wm row, e16>=8 -> Wn row.
// Grid (KSL, NB) = 1024 blocks (4 waves/SIMD), 256 thr = 16 e16 x 16 c.
// 4 independent accumulators break the FMA dependence chain (latency-bound fix).
// ---------------------------------------------------------------------------
__global__ __launch_bounds__(256) void gate_partial(
    const float* __restrict__ x,
    const float* __restrict__ Wm,
    const float* __restrict__ Wn,
    float* __restrict__ partial)
{
    const int b  = blockIdx.y;
    const int sl = blockIdx.x;
    const int c  = threadIdx.x & 15;
    const int e  = threadIdx.x >> 4;          // 0..15

    const float* __restrict__ Wrow = (e < 8) ? (Wm + e * (2 * NS))
                                             : (Wn + (e - 8) * (2 * NS));
    const float* __restrict__ xb = x + b * (NS * NC * 2) + c * 2;
    const int s_base = sl * (NS / KSL);       // 64 s per slice

    float a0 = 0.f, a1 = 0.f, a2 = 0.f, a3 = 0.f;
#define GP_PAIR(soff, acc)                                                    \
    {                                                                         \
        const int s = s_base + (soff);                                        \
        const float4 wv = *(const float4*)(Wrow + 2 * s);                     \
        const float2 x0 = *(const float2*)(xb + s * (NC * 2));                \
        const float2 x1 = *(const float2*)(xb + (s + 1) * (NC * 2));          \
        acc = fmaf(x0.x, wv.x, acc);                                          \
        acc = fmaf(x0.y, wv.y, acc);                                          \
        acc = fmaf(x1.x, wv.z, acc);                                          \
        acc = fmaf(x1.y, wv.w, acc);                                          \
    }
#pragma unroll 2
    for (int i = 0; i < NS / KSL; i += 8) {
        GP_PAIR(i + 0, a0)
        GP_PAIR(i + 2, a1)
        GP_PAIR(i + 4, a2)
        GP_PAIR(i + 6, a3)
    }
#undef GP_PAIR
    const float acc = (a0 + a1) + (a2 + a3);
    // layout [b][sl][e][c] so gate_final reads are lane-contiguous in c
    partial[(((b * KSL) + sl) * 16 + e) * 16 + c] = acc;
}

// ---------------------------------------------------------------------------
// Kernel A2: gate finalize. One thread per row r=(b,c): reduce slices,
// g = gm + bm + softplus(gn + bn); strict top-k mask (g > kth) + softmax,
// masked entries EXACT zero.
// ---------------------------------------------------------------------------
__global__ __launch_bounds__(64) void gate_final(
    const float* __restrict__ partial,
    const float* __restrict__ bm, const float* __restrict__ bn,
    const int* __restrict__ kptr,
    float* __restrict__ gates)
{
    const int r = blockIdx.x * 64 + threadIdx.x;   // 0..511
    const int b = r >> 4;
    const int c = r & 15;

    float g16[16];
#pragma unroll
    for (int e = 0; e < 16; ++e) g16[e] = 0.f;
    for (int sl = 0; sl < KSL; ++sl) {
        const float* p = partial + ((b * KSL + sl) * 16) * 16 + c;
#pragma unroll
        for (int e = 0; e < 16; ++e) g16[e] += p[e * 16];
    }

    float g[NE];
#pragma unroll
    for (int e = 0; e < NE; ++e) {
        const float gn = g16[e + 8] + bn[e];
        const float sp = (gn > 20.f) ? gn : __logf(1.f + __expf(gn));
        g[e] = g16[e] + bm[e] + sp;
    }

    // branchless 8-element sorting network (ascending), 19 comparators
    float s[NE];
#pragma unroll
    for (int e = 0; e < NE; ++e) s[e] = g[e];
#define CSWP(i, j) { float lo = fminf(s[i], s[j]); float hi = fmaxf(s[i], s[j]); s[i] = lo; s[j] = hi; }
    CSWP(0,1) CSWP(2,3) CSWP(4,5) CSWP(6,7)
    CSWP(0,2) CSWP(1,3) CSWP(4,6) CSWP(5,7)
    CSWP(1,2) CSWP(5,6)
    CSWP(0,4) CSWP(1,5) CSWP(2,6) CSWP(3,7)
    CSWP(2,4) CSWP(3,5)
    CSWP(1,2) CSWP(3,4) CSWP(5,6)
#undef CSWP

    const int k = *kptr;
    const float kth = s[NE - 1 - k];
    const float mx  = s[NE - 1];
    float gw[NE];
    float denom = 0.f;
#pragma unroll
    for (int e = 0; e < NE; ++e) {
        const float ex = __expf(g[e] - mx);
        const float keep = (g[e] > kth) ? ex : 0.f;
        gw[e] = keep;
        denom += keep;
    }
    const float inv = 1.f / denom;
    float4 o0 = make_float4(gw[0] * inv, gw[1] * inv, gw[2] * inv, gw[3] * inv);
    float4 o1 = make_float4(gw[4] * inv, gw[5] * inv, gw[6] * inv, gw[7] * inv);
    *(float4*)(gates + r * NE)     = o0;
    *(float4*)(gates + r * NE + 4) = o1;
}

// ---------------------------------------------------------------------------
// Fast nonlinearities (native exp/log based; abs err <= ~2e-6, budget 0.335)
// ---------------------------------------------------------------------------
template <int E> __device__ __forceinline__ float nlin(float v);
template <> __device__ __forceinline__ float nlin<0>(float v) { return fmaxf(v, 0.f); }   // relu
template <> __device__ __forceinline__ float nlin<1>(float v) {                           // tanh
    const float t = __expf(2.f * fminf(v, 15.f));
    return __fdividef(t - 1.f, t + 1.f);
}
template <> __device__ __forceinline__ float nlin<2>(float v) {                           // elu
    return v > 0.f ? v : (__expf(v) - 1.f);
}
template <> __device__ __forceinline__ float nlin<3>(float v) {                           // silu
    return __fdividef(v, 1.f + __expf(-v));
}
template <> __device__ __forceinline__ float nlin<4>(float v) { return v; }               // none
template <> __device__ __forceinline__ float nlin<5>(float v) {                           // gelu (erf, A&S 7.1.26)
    const float u  = v * 0.70710678118654752f;
    const float au = fabsf(u);
    const float t  = __fdividef(1.f, fmaf(0.3275911f, au, 1.f));
    float p = fmaf(1.061405429f, t, -1.453152027f);
    p = fmaf(p, t, 1.421413741f);
    p = fmaf(p, t, -0.284496736f);
    p = fmaf(p, t, 0.254829592f);
    const float y = 1.f - p * t * __expf(-u * u);
    const float erfv = copysignf(y, u);
    return 0.5f * v * (1.f + erfv);
}
template <> __device__ __forceinline__ float nlin<6>(float v) {                           // selu
    return 1.0507009873554805f * (v > 0.f ? v : 1.6732632423543772f * (__expf(v) - 1.f));
}
template <> __device__ __forceinline__ float nlin<7>(float v) {                           // softplus
    return (v > 20.f) ? v : __logf(1.f + __expf(v));
}

#define NPOS 4   // positions per thread: 4 independent chains through the trans pipe

template <int E>
__device__ __forceinline__ void expert_accum4(
    const float (&xx)[NPOS], const float (&xy)[NPOS], const float (&am)[NPOS], float ge,
    const float* __restrict__ W1, const float* __restrict__ b1,
    const float* __restrict__ W2, const float* __restrict__ b2,
    float (&ot0)[NPOS], float (&ot1)[NPOS])
{
    if (ge != 0.f) {   // wave-uniform (gate row shared by whole wave) -> execz skip
        float a0[NPOS], a1[NPOS];
#pragma unroll
        for (int j = 0; j < NPOS; ++j) { a0[j] = 0.f; a1[j] = 0.f; }
#pragma unroll
        for (int h = 0; h < NH; ++h) {
            const float w0  = W1[(E * NH + h) * 3 + 0];
            const float w1v = W1[(E * NH + h) * 3 + 1];
            const float w2v = W1[(E * NH + h) * 3 + 2];
            const float bb  = b1[E * NH + h];
            const float u0  = W2[E * 2 * NH + h];
            const float u1  = W2[E * 2 * NH + NH + h];
#pragma unroll
            for (int j = 0; j < NPOS; ++j) {
                const float pre = fmaf(w0, xx[j], fmaf(w1v, xy[j], fmaf(w2v, am[j], bb)));
                const float a = nlin<E>(pre);
                a0[j] = fmaf(u0, a, a0[j]);
                a1[j] = fmaf(u1, a, a1[j]);
            }
        }
        const float c0 = b2[E * 2 + 0];
        const float c1 = b2[E * 2 + 1];
#pragma unroll
        for (int j = 0; j < NPOS; ++j) {
            ot0[j] = fmaf(ge, a0[j] + c0, ot0[j]);
            ot1[j] = fmaf(ge, a1[j] + c1, ot1[j]);
        }
    }
}

// ---------------------------------------------------------------------------
// Kernel B: out[b,s,c,t] = sum_e gate[b*16+c,e] * Expert_e(x[b, c*128+(s>>4), s&15, :])
// Block (s_blk, b): s in [s0, s0+256), all 16 c. Wave w handles c=w, 4 pos/thread.
// Padded-LDS staging for coalesced float2 writes.
// ---------------------------------------------------------------------------
__global__ __launch_bounds__(1024) void expert_kernel(
    const float* __restrict__ x,
    const float* __restrict__ W1, const float* __restrict__ b1,
    const float* __restrict__ W2, const float* __restrict__ b2,
    const float* __restrict__ gates,
    float* __restrict__ out)
{
    const int b  = blockIdx.y;
    const int s0 = blockIdx.x * 256;
    const int c    = threadIdx.x >> 6;
    const int lane = threadIdx.x & 63;

    __shared__ float lds[256 * 34];   // [256 s_local][17 float2 slots] = 34 KB

    float g[NE];
    const float* grow = gates + (b * NC + c) * NE;
#pragma unroll
    for (int e = 0; e < NE; ++e) g[e] = grow[e];

    float xx[NPOS], xy[NPOS], am[NPOS], ot0[NPOS], ot1[NPOS];
#pragma unroll
    for (int j = 0; j < NPOS; ++j) { ot0[j] = 0.f; ot1[j] = 0.f; }
#pragma unroll
    for (int j = 0; j < NPOS; ++j) {
        const int s = s0 + lane + 64 * j;
        const float2 xv = *(const float2*)(x + b * (NS * NC * 2)
                                             + (c * 128 + (s >> 4)) * (NC * 2)
                                             + (s & 15) * 2);
        xx[j] = xv.x; xy[j] = xv.y;
        am[j] = sqrtf(fmaf(xv.x, xv.x, xv.y * xv.y));
    }

    expert_accum4<0>(xx, xy, am, g[0], W1, b1, W2, b2, ot0, ot1);
    expert_accum4<1>(xx, xy, am, g[1], W1, b1, W2, b2, ot0, ot1);
    expert_accum4<2>(xx, xy, am, g[2], W1, b1, W2, b2, ot0, ot1);
    expert_accum4<3>(xx, xy, am, g[3], W1, b1, W2, b2, ot0, ot1);
    expert_accum4<4>(xx, xy, am, g[4], W1, b1, W2, b2, ot0, ot1);
    expert_accum4<5>(xx, xy, am, g[5], W1, b1, W2, b2, ot0, ot1);
    expert_accum4<6>(xx, xy, am, g[6], W1, b1, W2, b2, ot0, ot1);
    expert_accum4<7>(xx, xy, am, g[7], W1, b1, W2, b2, ot0, ot1);

#pragma unroll
    for (int j = 0; j < NPOS; ++j) {
        const int sl = lane + 64 * j;
        lds[sl * 34 + c * 2 + 0] = ot0[j];
        lds[sl * 34 + c * 2 + 1] = ot1[j];
    }
    __syncthreads();

#pragma unroll
    for (int j = 0; j < NPOS; ++j) {
        const int m  = threadIdx.x + 1024 * j;
        const int sl = m >> 4;
        const int cc = m & 15;
        float2 v = make_float2(lds[sl * 34 + cc * 2], lds[sl * 34 + cc * 2 + 1]);
        *(float2*)(out + b * (NS * NC * 2) + (s0 + sl) * (NC * 2) + cc * 2) = v;
    }
}

extern "C" void kernel_launch(void* const* d_in, const int* in_sizes, int n_in,
                              void* d_out, int out_size, void* d_ws, size_t ws_size,
                              hipStream_t stream) {
    const float* x  = (const float*)d_in[0];
    const float* Wm = (const float*)d_in[1];
    const float* bm = (const float*)d_in[2];
    const float* Wn = (const float*)d_in[3];
    const float* bn = (const float*)d_in[4];
    const float* W1 = (const float*)d_in[5];
    const float* b1 = (const float*)d_in[6];
    const float* W2 = (const float*)d_in[7];
    const float* b2 = (const float*)d_in[8];
    const int*   kp = (const int*)d_in[9];
    float* out     = (float*)d_out;
    float* gates   = (float*)d_ws;                        // 512*8 floats    = 16 KB
    float* partial = (float*)d_ws + 4096;                 // 32*32*16*16 fl  = 1 MB

    dim3 gp_grid(KSL, NB);
    gate_partial<<<gp_grid, 256, 0, stream>>>(x, Wm, Wn, partial);
    gate_final<<<NB * NC / 64, 64, 0, stream>>>(partial, bm, bn, kp, gates);

    dim3 grid(NS / 256, NB);
    expert_kernel<<<grid, 1024, 0, stream>>>(x, W1, b1, W2, b2, gates, out);
}

// Round 12
// 108.278 us; speedup vs baseline: 1.3216x; 1.3216x over previous
//
#include <hip/hip_runtime.h>
#include <math.h>

// Problem constants: B=32, S=2048, C=16, E=8, H=16
#define NB 32
#define NS 2048
#define NC 16
#define NE 8
#define NH 16
#define KSL 16            // K-slices for gate partial GEMM (128 s per slice)
#define WPAD 260          // padded W-row length in LDS (16B-aligned, bank-spread)

// ---------------------------------------------------------------------------
// Kernel A1: gate partial sums, LDS-staged.
// g_pre[r=(b,c)][e16] = sum_K x2[r][K]*W[e16][K],  x2[(b,c)][2s+t]=x[b,s,c,t].
// Block (sl, b): stages x-tile [128 s][32 floats] (contiguous, coalesced) and
// W-chunk [16 rows][256 floats] into LDS, then thread (e,c) accumulates 128
// K-steps from LDS with 4 independent accumulators.
// ---------------------------------------------------------------------------
__global__ __launch_bounds__(256) void gate_partial(
    const float* __restrict__ x,
    const float* __restrict__ Wm,
    const float* __restrict__ Wn,
    float* __restrict__ partial)
{
    const int b  = blockIdx.y;
    const int sl = blockIdx.x;
    const int t  = threadIdx.x;

    __shared__ float xs[128 * 32];      // 16 KB, x[b, sl*128+i, c, tt] -> xs[i*32 + c*2 + tt]
    __shared__ float ws[16 * WPAD];     // 16.25 KB, row e16, cols 2s-chunk

    // ---- stage x: 4096 contiguous floats = 1024 float4, 4 per thread ----
    {
        const float* __restrict__ gx = x + b * (NS * NC * 2) + sl * 128 * 32;
#pragma unroll
        for (int rep = 0; rep < 4; ++rep) {
            const int idx = rep * 256 + t;              // float4 index
            *(float4*)(xs + 4 * idx) = *(const float4*)(gx + 4 * idx);
        }
    }
    // ---- stage W: 16 rows x 64 float4, 4 per thread (coalesced per row) ----
    {
#pragma unroll
        for (int rep = 0; rep < 4; ++rep) {
            const int idx  = rep * 256 + t;             // 0..1023
            const int row  = idx >> 6;                  // /64
            const int col4 = idx & 63;
            const float* __restrict__ gw =
                ((row < 8) ? (Wm + row * (2 * NS)) : (Wn + (row - 8) * (2 * NS)))
                + sl * 256 + col4 * 4;
            const float4 v = *(const float4*)gw;
            float* d = ws + row * WPAD + col4 * 4;      // row*WPAD*4B is 16B-aligned (WPAD=260)
            *(float4*)d = v;
        }
    }
    __syncthreads();

    // ---- compute: thread (e = t>>4, c = t&15), 128 K-steps from LDS ----
    const int c = t & 15;
    const int e = t >> 4;
    const float* __restrict__ wrow = ws + e * WPAD;
    const float* __restrict__ xcol = xs + 2 * c;

    float a0 = 0.f, a1 = 0.f, a2 = 0.f, a3 = 0.f;
#pragma unroll 8
    for (int i = 0; i < 128; i += 4) {
        const float2 w0 = *(const float2*)(wrow + 2 * (i + 0));
        const float2 w1 = *(const float2*)(wrow + 2 * (i + 1));
        const float2 w2 = *(const float2*)(wrow + 2 * (i + 2));
        const float2 w3 = *(const float2*)(wrow + 2 * (i + 3));
        const float2 x0 = *(const float2*)(xcol + 32 * (i + 0));
        const float2 x1 = *(const float2*)(xcol + 32 * (i + 1));
        const float2 x2 = *(const float2*)(xcol + 32 * (i + 2));
        const float2 x3 = *(const float2*)(xcol + 32 * (i + 3));
        a0 = fmaf(x0.x, w0.x, a0); a0 = fmaf(x0.y, w0.y, a0);
        a1 = fmaf(x1.x, w1.x, a1); a1 = fmaf(x1.y, w1.y, a1);
        a2 = fmaf(x2.x, w2.x, a2); a2 = fmaf(x2.y, w2.y, a2);
        a3 = fmaf(x3.x, w3.x, a3); a3 = fmaf(x3.y, w3.y, a3);
    }
    const float acc = (a0 + a1) + (a2 + a3);
    // layout [b][sl][e][c] so gate_final reads are lane-contiguous in c
    partial[(((b * KSL) + sl) * 16 + e) * 16 + c] = acc;
}

// ---------------------------------------------------------------------------
// Kernel A2: gate finalize. One thread per row r=(b,c): reduce slices,
// g = gm + bm + softplus(gn + bn); strict top-k mask (g > kth) + softmax,
// masked entries EXACT zero.
// ---------------------------------------------------------------------------
__global__ __launch_bounds__(64) void gate_final(
    const float* __restrict__ partial,
    const float* __restrict__ bm, const float* __restrict__ bn,
    const int* __restrict__ kptr,
    float* __restrict__ gates)
{
    const int r = blockIdx.x * 64 + threadIdx.x;   // 0..511
    const int b = r >> 4;
    const int c = r & 15;

    float g16[16];
#pragma unroll
    for (int e = 0; e < 16; ++e) g16[e] = 0.f;
    for (int sl = 0; sl < KSL; ++sl) {
        const float* p = partial + ((b * KSL + sl) * 16) * 16 + c;
#pragma unroll
        for (int e = 0; e < 16; ++e) g16[e] += p[e * 16];
    }

    float g[NE];
#pragma unroll
    for (int e = 0; e < NE; ++e) {
        const float gn = g16[e + 8] + bn[e];
        const float sp = (gn > 20.f) ? gn : __logf(1.f + __expf(gn));
        g[e] = g16[e] + bm[e] + sp;
    }

    // branchless 8-element sorting network (ascending), 19 comparators
    float s[NE];
#pragma unroll
    for (int e = 0; e < NE; ++e) s[e] = g[e];
#define CSWP(i, j) { float lo = fminf(s[i], s[j]); float hi = fmaxf(s[i], s[j]); s[i] = lo; s[j] = hi; }
    CSWP(0,1) CSWP(2,3) CSWP(4,5) CSWP(6,7)
    CSWP(0,2) CSWP(1,3) CSWP(4,6) CSWP(5,7)
    CSWP(1,2) CSWP(5,6)
    CSWP(0,4) CSWP(1,5) CSWP(2,6) CSWP(3,7)
    CSWP(2,4) CSWP(3,5)
    CSWP(1,2) CSWP(3,4) CSWP(5,6)
#undef CSWP

    const int k = *kptr;
    const float kth = s[NE - 1 - k];
    const float mx  = s[NE - 1];
    float gw[NE];
    float denom = 0.f;
#pragma unroll
    for (int e = 0; e < NE; ++e) {
        const float ex = __expf(g[e] - mx);
        const float keep = (g[e] > kth) ? ex : 0.f;
        gw[e] = keep;
        denom += keep;
    }
    const float inv = 1.f / denom;
    float4 o0 = make_float4(gw[0] * inv, gw[1] * inv, gw[2] * inv, gw[3] * inv);
    float4 o1 = make_float4(gw[4] * inv, gw[5] * inv, gw[6] * inv, gw[7] * inv);
    *(float4*)(gates + r * NE)     = o0;
    *(float4*)(gates + r * NE + 4) = o1;
}

// ---------------------------------------------------------------------------
// Fast nonlinearities (native exp/log based; abs err <= ~2e-6, budget 0.335)
// ---------------------------------------------------------------------------
template <int E> __device__ __forceinline__ float nlin(float v);
template <> __device__ __forceinline__ float nlin<0>(float v) { return fmaxf(v, 0.f); }   // relu
template <> __device__ __forceinline__ float nlin<1>(float v) {                           // tanh
    const float t = __expf(2.f * fminf(v, 15.f));
    return __fdividef(t - 1.f, t + 1.f);
}
template <> __device__ __forceinline__ float nlin<2>(float v) {                           // elu
    return v > 0.f ? v : (__expf(v) - 1.f);
}
template <> __device__ __forceinline__ float nlin<3>(float v) {                           // silu
    return __fdividef(v, 1.f + __expf(-v));
}
template <> __device__ __forceinline__ float nlin<4>(float v) { return v; }               // none
template <> __device__ __forceinline__ float nlin<5>(float v) {                           // gelu (erf, A&S 7.1.26)
    const float u  = v * 0.70710678118654752f;
    const float au = fabsf(u);
    const float t  = __fdividef(1.f, fmaf(0.3275911f, au, 1.f));
    float p = fmaf(1.061405429f, t, -1.453152027f);
    p = fmaf(p, t, 1.421413741f);
    p = fmaf(p, t, -0.284496736f);
    p = fmaf(p, t, 0.254829592f);
    const float y = 1.f - p * t * __expf(-u * u);
    const float erfv = copysignf(y, u);
    return 0.5f * v * (1.f + erfv);
}
template <> __device__ __forceinline__ float nlin<6>(float v) {                           // selu
    return 1.0507009873554805f * (v > 0.f ? v : 1.6732632423543772f * (__expf(v) - 1.f));
}
template <> __device__ __forceinline__ float nlin<7>(float v) {                           // softplus
    return (v > 20.f) ? v : __logf(1.f + __expf(v));
}

// Process BOTH per-thread positions inside one gate-guarded block:
// weights loaded once, two independent chains through the transcendental.
template <int E>
__device__ __forceinline__ void expert_accum2(
    const float (&xx)[2], const float (&xy)[2], const float (&am)[2], float ge,
    const float* __restrict__ W1, const float* __restrict__ b1,
    const float* __restrict__ W2, const float* __restrict__ b2,
    float (&ot0)[2], float (&ot1)[2])
{
    if (ge != 0.f) {   // wave-uniform (gate row shared by whole wave) -> execz skip
        float a0[2] = {0.f, 0.f}, a1[2] = {0.f, 0.f};
#pragma unroll
        for (int h = 0; h < NH; ++h) {
            const float w0  = W1[(E * NH + h) * 3 + 0];
            const float w1v = W1[(E * NH + h) * 3 + 1];
            const float w2v = W1[(E * NH + h) * 3 + 2];
            const float bb  = b1[E * NH + h];
            const float u0  = W2[E * 2 * NH + h];
            const float u1  = W2[E * 2 * NH + NH + h];
#pragma unroll
            for (int j = 0; j < 2; ++j) {
                const float pre = fmaf(w0, xx[j], fmaf(w1v, xy[j], fmaf(w2v, am[j], bb)));
                const float a = nlin<E>(pre);
                a0[j] = fmaf(u0, a, a0[j]);
                a1[j] = fmaf(u1, a, a1[j]);
            }
        }
        const float c0 = b2[E * 2 + 0];
        const float c1 = b2[E * 2 + 1];
#pragma unroll
        for (int j = 0; j < 2; ++j) {
            ot0[j] = fmaf(ge, a0[j] + c0, ot0[j]);
            ot1[j] = fmaf(ge, a1[j] + c1, ot1[j]);
        }
    }
}

// ---------------------------------------------------------------------------
// Kernel B: out[b,s,c,t] = sum_e gate[b*16+c,e] * Expert_e(x[b, c*128+(s>>4), s&15, :])
// Block (s_blk, b): s in [s0, s0+128), all 16 c. Wave w handles c=w.
// Padded-LDS staging for coalesced float2 writes.
// (Reverted verbatim to the round-2 config measured at ~20 us, VGPR 36.)
// ---------------------------------------------------------------------------
__global__ __launch_bounds__(1024) void expert_kernel(
    const float* __restrict__ x,
    const float* __restrict__ W1, const float* __restrict__ b1,
    const float* __restrict__ W2, const float* __restrict__ b2,
    const float* __restrict__ gates,
    float* __restrict__ out)
{
    const int b  = blockIdx.y;
    const int s0 = blockIdx.x * 128;
    const int c    = threadIdx.x >> 6;
    const int lane = threadIdx.x & 63;

    __shared__ float lds[128 * 34];   // [128 s_local][17 float2 slots]

    float g[NE];
    const float* grow = gates + (b * NC + c) * NE;
#pragma unroll
    for (int e = 0; e < NE; ++e) g[e] = grow[e];

    float xx[2], xy[2], am[2], ot0[2] = {0.f, 0.f}, ot1[2] = {0.f, 0.f};
#pragma unroll
    for (int j = 0; j < 2; ++j) {
        const int s = s0 + lane + 64 * j;
        const float2 xv = *(const float2*)(x + b * (NS * NC * 2)
                                             + (c * 128 + (s >> 4)) * (NC * 2)
                                             + (s & 15) * 2);
        xx[j] = xv.x; xy[j] = xv.y;
        am[j] = sqrtf(fmaf(xv.x, xv.x, xv.y * xv.y));
    }

    expert_accum2<0>(xx, xy, am, g[0], W1, b1, W2, b2, ot0, ot1);
    expert_accum2<1>(xx, xy, am, g[1], W1, b1, W2, b2, ot0, ot1);
    expert_accum2<2>(xx, xy, am, g[2], W1, b1, W2, b2, ot0, ot1);
    expert_accum2<3>(xx, xy, am, g[3], W1, b1, W2, b2, ot0, ot1);
    expert_accum2<4>(xx, xy, am, g[4], W1, b1, W2, b2, ot0, ot1);
    expert_accum2<5>(xx, xy, am, g[5], W1, b1, W2, b2, ot0, ot1);
    expert_accum2<6>(xx, xy, am, g[6], W1, b1, W2, b2, ot0, ot1);
    expert_accum2<7>(xx, xy, am, g[7], W1, b1, W2, b2, ot0, ot1);

#pragma unroll
    for (int j = 0; j < 2; ++j) {
        const int sl = lane + 64 * j;
        lds[sl * 34 + c * 2 + 0] = ot0[j];
        lds[sl * 34 + c * 2 + 1] = ot1[j];
    }
    __syncthreads();

#pragma unroll
    for (int j = 0; j < 2; ++j) {
        const int m  = threadIdx.x + 1024 * j;
        const int sl = m >> 4;
        const int cc = m & 15;
        float2 v = make_float2(lds[sl * 34 + cc * 2], lds[sl * 34 + cc * 2 + 1]);
        *(float2*)(out + b * (NS * NC * 2) + (s0 + sl) * (NC * 2) + cc * 2) = v;
    }
}

extern "C" void kernel_launch(void* const* d_in, const int* in_sizes, int n_in,
                              void* d_out, int out_size, void* d_ws, size_t ws_size,
                              hipStream_t stream) {
    const float* x  = (const float*)d_in[0];
    const float* Wm = (const float*)d_in[1];
    const float* bm = (const float*)d_in[2];
    const float* Wn = (const float*)d_in[3];
    const float* bn = (const float*)d_in[4];
    const float* W1 = (const float*)d_in[5];
    const float* b1 = (const float*)d_in[6];
    const float* W2 = (const float*)d_in[7];
    const float* b2 = (const float*)d_in[8];
    const int*   kp = (const int*)d_in[9];
    float* out     = (float*)d_out;
    float* gates   = (float*)d_ws;                        // 512*8 floats   = 16 KB
    float* partial = (float*)d_ws + 4096;                 // 32*16*16*16 fl = 512 KB

    dim3 gp_grid(KSL, NB);
    gate_partial<<<gp_grid, 256, 0, stream>>>(x, Wm, Wn, partial);
    gate_final<<<NB * NC / 64, 64, 0, stream>>>(partial, bm, bn, kp, gates);

    dim3 grid(NS / 128, NB);
    expert_kernel<<<grid, 1024, 0, stream>>>(x, W1, b1, W2, b2, gates, out);
}